// Round 7
// baseline (1055.866 us; speedup 1.0000x reference)
//
#include <hip/hip_runtime.h>
#include <hip/hip_fp16.h>
#include <math.h>

#define Q    4096
#define NN   16384
#define DD   256
#define KSEL 33
#define LSTR 80    // staging LDS row stride bytes: 64 B data (32 f16) + 16 B pad
#define OSTR 264   // epilogue LDS row stride bytes: 256 B data + 8 B pad

typedef __attribute__((ext_vector_type(8))) _Float16 half8;
typedef __attribute__((ext_vector_type(4))) float    floatx4;

__device__ __forceinline__ float h2f(unsigned short u) {
    union { unsigned short s; _Float16 h; } c; c.s = u;
    return (float)c.h;
}
// f32 -> f16 raw bits, guaranteed FINITE pattern (exp field != 0x1F)
__device__ __forceinline__ unsigned short f2h_finite(float v) {
    v = fminf(fmaxf(v, -65504.0f), 65504.0f);       // IEEE fmax/fmin: NaN -> -65504
    union { _Float16 h; unsigned short s; } c; c.h = (_Float16)v;
    unsigned short u = c.s;
    if ((u & 0x7C00u) == 0x7C00u) u = (u & 0x8000u) ? 0xFBFFu : 0x7BFFu;
    return u;
}
__device__ __forceinline__ unsigned int patch16(unsigned int u) {   // u: 16-bit f16 bits
    if ((u & 0x7C00u) == 0x7C00u) u = (u & 0x8000u) ? 0xFBFFu : 0x7BFFu;
    return u;
}

// ---------------------------------------------------------------- row norms -> ws
__global__ __launch_bounds__(64) void norms_kernel(const unsigned short* __restrict__ x,
                                                   const unsigned short* __restrict__ xn,
                                                   float* __restrict__ ws) {
    const int row = blockIdx.x;                 // [0, Q+NN)
    const unsigned short* src = (row < Q) ? (x + (size_t)row * DD)
                                          : (xn + (size_t)(row - Q) * DD);
    const int t = threadIdx.x;                  // 64 threads x 4 f16
    const uint2 v = ((const uint2*)src)[t];
    float s = 0.f;
    {
        const float a = h2f(v.x & 0xFFFF), b = h2f(v.x >> 16);
        const float c = h2f(v.y & 0xFFFF), d = h2f(v.y >> 16);
        s = a * a + b * b + c * c + d * d;
    }
    for (int off = 32; off > 0; off >>= 1) s += __shfl_down(s, off);
    if (t == 0) ws[row] = s;                    // ws[0..Q)=x2, ws[Q..Q+NN)=y2
}

// ---------------------------------------------------------------- sim GEMM (MFMA f16)
template <bool WS>
__global__ __launch_bounds__(256) void gemm_sim_kernel(const unsigned short* __restrict__ A,
                                                       const unsigned short* __restrict__ B,
                                                       const float* __restrict__ ws,
                                                       unsigned short* __restrict__ out) {
    __shared__ char  lds[128 * OSTR];   // staging during K-loop, transpose buf in epilogue
    __shared__ float s_x2[128];
    __shared__ float s_y2[128];
    char* ldsA = lds;
    char* ldsB = lds + 128 * LSTR;

    const int t    = threadIdx.x;
    const int m0   = blockIdx.y * 128;
    const int n0   = blockIdx.x * 128;
    const int wave = t >> 6;
    const int lane = t & 63;
    const int wm   = (wave & 1) << 6;
    const int wn   = (wave >> 1) << 6;
    const int l15  = lane & 15;
    const int quad = lane >> 4;
    const int r0   = t >> 2;
    const int qq   = t & 3;

    if (WS) {   // made visible by the K-loop's first __syncthreads
        if (t < 128) s_x2[t] = ws[m0 + t];
        else         s_y2[t - 128] = ws[Q + n0 + (t - 128)];
    }

    floatx4 acc[4][4];
#pragma unroll
    for (int i = 0; i < 4; ++i)
#pragma unroll
        for (int j = 0; j < 4; ++j) {
            acc[i][j][0] = 0.f; acc[i][j][1] = 0.f; acc[i][j][2] = 0.f; acc[i][j][3] = 0.f;
        }
    float pa[2] = {0.f, 0.f}, pb[2] = {0.f, 0.f};

    for (int k0 = 0; k0 < DD; k0 += 32) {
        float4 ar[2], br[2];
#pragma unroll
        for (int j = 0; j < 2; ++j) {
            const int r = r0 + (j << 6);
            ar[j] = *(const float4*)(A + (size_t)(m0 + r) * DD + k0 + qq * 8);
            br[j] = *(const float4*)(B + (size_t)(n0 + r) * DD + k0 + qq * 8);
            if (!WS) {
                const unsigned short* ua = (const unsigned short*)&ar[j];
                const unsigned short* ub = (const unsigned short*)&br[j];
#pragma unroll
                for (int e = 0; e < 8; ++e) {
                    const float fa = h2f(ua[e]); pa[j] = fmaf(fa, fa, pa[j]);
                    const float fb = h2f(ub[e]); pb[j] = fmaf(fb, fb, pb[j]);
                }
            }
        }
        __syncthreads();
#pragma unroll
        for (int j = 0; j < 2; ++j) {
            const int r = r0 + (j << 6);
            *(float4*)(ldsA + r * LSTR + qq * 16) = ar[j];
            *(float4*)(ldsB + r * LSTR + qq * 16) = br[j];
        }
        __syncthreads();
        half8 af[4], bg[4];
#pragma unroll
        for (int s = 0; s < 4; ++s) {
            af[s] = *(const half8*)(ldsA + (wm + s * 16 + l15) * LSTR + quad * 16);
            bg[s] = *(const half8*)(ldsB + (wn + s * 16 + l15) * LSTR + quad * 16);
        }
#pragma unroll
        for (int si = 0; si < 4; ++si)
#pragma unroll
            for (int sj = 0; sj < 4; ++sj)
                acc[si][sj] = __builtin_amdgcn_mfma_f32_16x16x32_f16(af[si], bg[sj], acc[si][sj], 0, 0, 0);
    }

    if (!WS) {
#pragma unroll
        for (int j = 0; j < 2; ++j) {
            pa[j] += __shfl_xor(pa[j], 1); pa[j] += __shfl_xor(pa[j], 2);
            pb[j] += __shfl_xor(pb[j], 1); pb[j] += __shfl_xor(pb[j], 2);
        }
        if (qq == 0) {
            s_x2[r0] = pa[0]; s_x2[64 + r0] = pa[1];
            s_y2[r0] = pb[0]; s_y2[64 + r0] = pb[1];
        }
    }
    __syncthreads();   // staging reads done -> lds reusable; norms visible

    // epilogue pass 1: acc -> f16 into LDS transpose buffer
    // C/D layout: col = lane&15, row = quad*4 + reg  [measured m89; dtype-independent]
#pragma unroll
    for (int si = 0; si < 4; ++si) {
#pragma unroll
        for (int r = 0; r < 4; ++r) {
            const int lrow = wm + si * 16 + quad * 4 + r;
            const float xv = s_x2[lrow];
#pragma unroll
            for (int sj = 0; sj < 4; ++sj) {
                const int lcol = wn + sj * 16 + l15;
                float d2 = fmaxf(xv + s_y2[lcol] - 2.0f * acc[si][sj][r], 0.0f);
                d2 = fminf(d2, 1e9f);
                *(unsigned short*)(lds + lrow * OSTR + lcol * 2) = f2h_finite(-sqrtf(d2));
            }
        }
    }
    __syncthreads();

    // epilogue pass 2: coalesced 16B stores
#pragma unroll
    for (int p = 0; p < 8; ++p) {
        const int idx = p * 256 + t;
        const int r = idx >> 4, c = idx & 15;
        *(uint4*)(out + (size_t)(m0 + r) * NN + n0 + c * 8) = *(const uint4*)(lds + r * OSTR + c * 16);
    }
}

// ---------------------------------------------------------------- top-33 + mask (register-resident)
// One block per row. Thread t owns 8 uint4 chunks (64 f16) at uint4-index j*256+t.
// gi = 2048*j + 8*t + e ; ordinal = j*8+e (ascending ordinal == ascending gi per thread).
__global__ __launch_bounds__(256) void topk_kernel(unsigned short* __restrict__ out) {
    const int row = blockIdx.x;
    unsigned short* rowp = out + (size_t)row * NN;
    const int t = threadIdx.x;

    __shared__ float s_val[256];
    __shared__ int   s_idx[256];
    __shared__ int   s_wini;

    uint4 data[8];
    const uint4* rp4 = (const uint4*)rowp;
#pragma unroll
    for (int j = 0; j < 8; ++j) data[j] = rp4[j * 256 + t];

    const float NEG = -1.0e9f;
    unsigned long long consumed = 0ull;

    // initial per-thread top-2 (strict > keeps lowest gi among equals)
    float b1v = NEG, b2v = NEG; int b1l = -1, b2l = -1;
#pragma unroll
    for (int j = 0; j < 8; ++j) {
        const unsigned int* w = (const unsigned int*)&data[j];
#pragma unroll
        for (int e = 0; e < 8; ++e) {
            const unsigned int u = (e & 1) ? (w[e >> 1] >> 16) : (w[e >> 1] & 0xFFFFu);
            const float v = h2f((unsigned short)u);
            const int lo = j * 8 + e;
            if (v > b1v)      { b2v = b1v; b2l = b1l; b1v = v; b1l = lo; }
            else if (v > b2v) { b2v = v; b2l = lo; }
        }
    }
    s_val[t] = b1v;
    s_idx[t] = (b1l >= 0) ? (((b1l >> 3) << 11) + (t << 3) + (b1l & 7)) : 0x7fffffff;
    __syncthreads();

    for (int k = 0; k < KSEL; ++k) {
        if (t < 64) {   // wave-0 argmax over 256 candidates, tie-break lowest gi
            float mv = s_val[t]; int mi = s_idx[t];
#pragma unroll
            for (int c = 1; c < 4; ++c) {
                const float v = s_val[t + 64 * c]; const int gi = s_idx[t + 64 * c];
                if (v > mv || (v == mv && gi < mi)) { mv = v; mi = gi; }
            }
            for (int off = 32; off > 0; off >>= 1) {
                const float ov = __shfl_down(mv, off);
                const int   oi = __shfl_down(mi, off);
                if (ov > mv || (ov == mv && oi < mi)) { mv = ov; mi = oi; }
            }
            if (t == 0) s_wini = mi;
        }
        __syncthreads();
        const int wi = s_wini;
        if (((wi >> 3) & 255) == t) {       // owner pops
            consumed |= 1ull << (((wi >> 11) << 3) | (wi & 7));
            if (b2l >= 0) {                 // promote cached backup: O(1)
                s_val[t] = b2v;
                s_idx[t] = ((b2l >> 3) << 11) + (t << 3) + (b2l & 7);
                b2l = -1; b2v = NEG;
            } else {                        // rare: rescan registers (no memory)
                float n1v = NEG, n2v = NEG; int n1l = -1, n2l = -1;
#pragma unroll
                for (int j = 0; j < 8; ++j) {
                    const unsigned int* w = (const unsigned int*)&data[j];
#pragma unroll
                    for (int e = 0; e < 8; ++e) {
                        const int lo = j * 8 + e;
                        if ((consumed >> lo) & 1ull) continue;
                        const unsigned int u = (e & 1) ? (w[e >> 1] >> 16) : (w[e >> 1] & 0xFFFFu);
                        const float v = h2f((unsigned short)u);
                        if (v > n1v)      { n2v = n1v; n2l = n1l; n1v = v; n1l = lo; }
                        else if (v > n2v) { n2v = v; n2l = lo; }
                    }
                }
                s_val[t] = n1v;
                s_idx[t] = (n1l >= 0) ? (((n1l >> 3) << 11) + (t << 3) + (n1l & 7)) : 0x7fffffff;
                b2v = n2v; b2l = n2l;
            }
        }
        __syncthreads();
    }

    // writeback: own chunks only — selected (=consumed) keep original bits (patched
    // finite), everything else = most-negative finite f16. No scatter, no race.
    uint4* wp4 = (uint4*)rowp;
#pragma unroll
    for (int j = 0; j < 8; ++j) {
        uint4 o;
        unsigned int* ow = (unsigned int*)&o;
        const unsigned int* w = (const unsigned int*)&data[j];
#pragma unroll
        for (int ww = 0; ww < 4; ++ww) {
            const int ord = j * 8 + ww * 2;
            const unsigned int lo16 = ((consumed >> ord) & 1ull)       ? patch16(w[ww] & 0xFFFFu) : 0xFBFFu;
            const unsigned int hi16 = ((consumed >> (ord + 1)) & 1ull) ? patch16(w[ww] >> 16)     : 0xFBFFu;
            ow[ww] = lo16 | (hi16 << 16);
        }
        wp4[j * 256 + t] = o;
    }
}

// ---------------------------------------------------------------- launch
extern "C" void kernel_launch(void* const* d_in, const int* in_sizes, int n_in,
                              void* d_out, int out_size, void* d_ws, size_t ws_size,
                              hipStream_t stream) {
    const unsigned short* x  = (const unsigned short*)d_in[0];   // [4096 x 256] f16
    const unsigned short* xn = (const unsigned short*)d_in[1];   // [16384 x 256] f16
    unsigned short* out = (unsigned short*)d_out;                // [4096 x 16384] f16
    float* ws = (float*)d_ws;

    const bool use_ws = ws_size >= (size_t)(Q + NN) * sizeof(float);
    if (use_ws) {
        norms_kernel<<<Q + NN, 64, 0, stream>>>(x, xn, ws);
        gemm_sim_kernel<true><<<dim3(NN / 128, Q / 128), 256, 0, stream>>>(x, xn, ws, out);
    } else {
        gemm_sim_kernel<false><<<dim3(NN / 128, Q / 128), 256, 0, stream>>>(x, xn, nullptr, out);
    }
    topk_kernel<<<Q, 256, 0, stream>>>(out);
}

// Round 8
// 671.385 us; speedup vs baseline: 1.5727x; 1.5727x over previous
//
#include <hip/hip_runtime.h>
#include <hip/hip_fp16.h>
#include <math.h>

#define Q    4096
#define NN   16384
#define DD   256
#define KSEL 33
#define LSTR 80    // staging LDS row stride bytes: 64 B data (32 f16) + 16 B pad
#define OSTR 264   // epilogue LDS row stride bytes: 256 B data + 8 B pad
#define CAND 96    // per-wave candidate cap (>= 33; overflow astronomically unlikely)

typedef __attribute__((ext_vector_type(8))) _Float16 half8;
typedef __attribute__((ext_vector_type(4))) float    floatx4;

__device__ __forceinline__ float h2f(unsigned short u) {
    union { unsigned short s; _Float16 h; } c; c.s = u;
    return (float)c.h;
}
// f32 -> f16 raw bits, guaranteed FINITE pattern (exp field != 0x1F)
__device__ __forceinline__ unsigned short f2h_finite(float v) {
    v = fminf(fmaxf(v, -65504.0f), 65504.0f);       // IEEE fmax/fmin: NaN -> -65504
    union { _Float16 h; unsigned short s; } c; c.h = (_Float16)v;
    unsigned short u = c.s;
    if ((u & 0x7C00u) == 0x7C00u) u = (u & 0x8000u) ? 0xFBFFu : 0x7BFFu;
    return u;
}
__device__ __forceinline__ unsigned int patch16(unsigned int u) {
    if ((u & 0x7C00u) == 0x7C00u) u = (u & 0x8000u) ? 0xFBFFu : 0x7BFFu;
    return u;
}
// monotone f16-bits -> sortable u16 (larger float => larger key); involutive pair
__device__ __forceinline__ unsigned int key_of(unsigned int u) {
    return (u & 0x8000u) ? (u ^ 0xFFFFu) : (u | 0x8000u);
}
__device__ __forceinline__ unsigned int inv_key(unsigned int k) {
    return (k & 0x8000u) ? (k ^ 0x8000u) : (~k & 0xFFFFu);
}

// ---------------------------------------------------------------- row norms -> ws
__global__ __launch_bounds__(64) void norms_kernel(const unsigned short* __restrict__ x,
                                                   const unsigned short* __restrict__ xn,
                                                   float* __restrict__ ws) {
    const int row = blockIdx.x;
    const unsigned short* src = (row < Q) ? (x + (size_t)row * DD)
                                          : (xn + (size_t)(row - Q) * DD);
    const int t = threadIdx.x;
    const uint2 v = ((const uint2*)src)[t];
    float s;
    {
        const float a = h2f(v.x & 0xFFFF), b = h2f(v.x >> 16);
        const float c = h2f(v.y & 0xFFFF), d = h2f(v.y >> 16);
        s = a * a + b * b + c * c + d * d;
    }
    for (int off = 32; off > 0; off >>= 1) s += __shfl_down(s, off);
    if (t == 0) ws[row] = s;
}

// ---------------------------------------------------------------- sim GEMM (MFMA f16) — unchanged from round 7
template <bool WS>
__global__ __launch_bounds__(256) void gemm_sim_kernel(const unsigned short* __restrict__ A,
                                                       const unsigned short* __restrict__ B,
                                                       const float* __restrict__ ws,
                                                       unsigned short* __restrict__ out) {
    __shared__ char  lds[128 * OSTR];
    __shared__ float s_x2[128];
    __shared__ float s_y2[128];
    char* ldsA = lds;
    char* ldsB = lds + 128 * LSTR;

    const int t    = threadIdx.x;
    const int m0   = blockIdx.y * 128;
    const int n0   = blockIdx.x * 128;
    const int wave = t >> 6;
    const int lane = t & 63;
    const int wm   = (wave & 1) << 6;
    const int wn   = (wave >> 1) << 6;
    const int l15  = lane & 15;
    const int quad = lane >> 4;
    const int r0   = t >> 2;
    const int qq   = t & 3;

    if (WS) {
        if (t < 128) s_x2[t] = ws[m0 + t];
        else         s_y2[t - 128] = ws[Q + n0 + (t - 128)];
    }

    floatx4 acc[4][4];
#pragma unroll
    for (int i = 0; i < 4; ++i)
#pragma unroll
        for (int j = 0; j < 4; ++j) {
            acc[i][j][0] = 0.f; acc[i][j][1] = 0.f; acc[i][j][2] = 0.f; acc[i][j][3] = 0.f;
        }
    float pa[2] = {0.f, 0.f}, pb[2] = {0.f, 0.f};

    for (int k0 = 0; k0 < DD; k0 += 32) {
        float4 ar[2], br[2];
#pragma unroll
        for (int j = 0; j < 2; ++j) {
            const int r = r0 + (j << 6);
            ar[j] = *(const float4*)(A + (size_t)(m0 + r) * DD + k0 + qq * 8);
            br[j] = *(const float4*)(B + (size_t)(n0 + r) * DD + k0 + qq * 8);
            if (!WS) {
                const unsigned short* ua = (const unsigned short*)&ar[j];
                const unsigned short* ub = (const unsigned short*)&br[j];
#pragma unroll
                for (int e = 0; e < 8; ++e) {
                    const float fa = h2f(ua[e]); pa[j] = fmaf(fa, fa, pa[j]);
                    const float fb = h2f(ub[e]); pb[j] = fmaf(fb, fb, pb[j]);
                }
            }
        }
        __syncthreads();
#pragma unroll
        for (int j = 0; j < 2; ++j) {
            const int r = r0 + (j << 6);
            *(float4*)(ldsA + r * LSTR + qq * 16) = ar[j];
            *(float4*)(ldsB + r * LSTR + qq * 16) = br[j];
        }
        __syncthreads();
        half8 af[4], bg[4];
#pragma unroll
        for (int s = 0; s < 4; ++s) {
            af[s] = *(const half8*)(ldsA + (wm + s * 16 + l15) * LSTR + quad * 16);
            bg[s] = *(const half8*)(ldsB + (wn + s * 16 + l15) * LSTR + quad * 16);
        }
#pragma unroll
        for (int si = 0; si < 4; ++si)
#pragma unroll
            for (int sj = 0; sj < 4; ++sj)
                acc[si][sj] = __builtin_amdgcn_mfma_f32_16x16x32_f16(af[si], bg[sj], acc[si][sj], 0, 0, 0);
    }

    if (!WS) {
#pragma unroll
        for (int j = 0; j < 2; ++j) {
            pa[j] += __shfl_xor(pa[j], 1); pa[j] += __shfl_xor(pa[j], 2);
            pb[j] += __shfl_xor(pb[j], 1); pb[j] += __shfl_xor(pb[j], 2);
        }
        if (qq == 0) {
            s_x2[r0] = pa[0]; s_x2[64 + r0] = pa[1];
            s_y2[r0] = pb[0]; s_y2[64 + r0] = pb[1];
        }
    }
    __syncthreads();

#pragma unroll
    for (int si = 0; si < 4; ++si) {
#pragma unroll
        for (int r = 0; r < 4; ++r) {
            const int lrow = wm + si * 16 + quad * 4 + r;
            const float xv = s_x2[lrow];
#pragma unroll
            for (int sj = 0; sj < 4; ++sj) {
                const int lcol = wn + sj * 16 + l15;
                float d2 = fmaxf(xv + s_y2[lcol] - 2.0f * acc[si][sj][r], 0.0f);
                d2 = fminf(d2, 1e9f);
                *(unsigned short*)(lds + lrow * OSTR + lcol * 2) = f2h_finite(-sqrtf(d2));
            }
        }
    }
    __syncthreads();

#pragma unroll
    for (int p = 0; p < 8; ++p) {
        const int idx = p * 256 + t;
        const int r = idx >> 4, c = idx & 15;
        *(uint4*)(out + (size_t)(m0 + r) * NN + n0 + c * 8) = *(const uint4*)(lds + r * OSTR + c * 16);
    }
}

// ---------------------------------------------------------------- top-33 via radix bit-select (2 barriers)
// One block per row; thread t owns uint4 chunks j*256+t; gi = 2048j + 8t + e.
// Wave w autonomously finds its local rank-33 key threshold (shuffle-only),
// emits candidates to LDS; wave 0 merges; all threads write back predicated.
__global__ __launch_bounds__(256) void topk_kernel(unsigned short* __restrict__ out) {
    const int row = blockIdx.x;
    unsigned short* rowp = out + (size_t)row * NN;
    const int t = threadIdx.x;
    const int lane = t & 63;
    const int wave = t >> 6;

    __shared__ unsigned int s_cand[4][CAND];   // (key<<16) | gi
    __shared__ int          s_cnum[4];
    __shared__ unsigned int s_tau;
    __shared__ int          s_nsel;
    __shared__ int          s_selgi[40];

    // load + transform to sortable keys in-place
    uint4 d[8];
    const uint4* rp4 = (const uint4*)rowp;
#pragma unroll
    for (int j = 0; j < 8; ++j) d[j] = rp4[j * 256 + t];
#pragma unroll
    for (int j = 0; j < 8; ++j) {
        unsigned int* w = (unsigned int*)&d[j];
#pragma unroll
        for (int q = 0; q < 4; ++q)
            w[q] = key_of(w[q] & 0xFFFFu) | (key_of(w[q] >> 16) << 16);
    }

    // ---- wave-local binary search on key bits for local rank-KSEL threshold
    unsigned int tau = 0;
#pragma unroll
    for (int b = 15; b >= 0; --b) {
        const unsigned int tc = tau | (1u << b);
        int c = 0;
#pragma unroll
        for (int j = 0; j < 8; ++j) {
            const unsigned int* w = (const unsigned int*)&d[j];
#pragma unroll
            for (int q = 0; q < 4; ++q)
                c += (int)((w[q] & 0xFFFFu) >= tc) + (int)((w[q] >> 16) >= tc);
        }
#pragma unroll
        for (int off = 1; off < 64; off <<= 1) c += __shfl_xor(c, off);
        if (c >= KSEL) tau = tc;            // wave-uniform
    }

    // ---- emit candidates (key >= tau): lane-exclusive-prefix slots
    int cge = 0;
#pragma unroll
    for (int j = 0; j < 8; ++j) {
        const unsigned int* w = (const unsigned int*)&d[j];
#pragma unroll
        for (int q = 0; q < 4; ++q)
            cge += (int)((w[q] & 0xFFFFu) >= tau) + (int)((w[q] >> 16) >= tau);
    }
    int p = cge;
#pragma unroll
    for (int off = 1; off < 64; off <<= 1) {
        const int v = __shfl_up(p, off);
        if (lane >= off) p += v;
    }
    int slot = p - cge;   // exclusive prefix
#pragma unroll
    for (int j = 0; j < 8; ++j) {
        const unsigned int* w = (const unsigned int*)&d[j];
#pragma unroll
        for (int q = 0; q < 4; ++q) {
#pragma unroll
            for (int h = 0; h < 2; ++h) {
                const unsigned int k = h ? (w[q] >> 16) : (w[q] & 0xFFFFu);
                if (k >= tau) {
                    if (slot < CAND)
                        s_cand[wave][slot] = (k << 16) | (unsigned int)((j << 11) + (t << 3) + q * 2 + h);
                    ++slot;
                }
            }
        }
    }
    if (lane == 63) s_cnum[wave] = (p < CAND) ? p : CAND;
    __syncthreads();                         // barrier 1

    // ---- wave-0 merge of <= 4*CAND candidates
    if (wave == 0) {
        const int n0c = s_cnum[0], n1c = s_cnum[1], n2c = s_cnum[2], n3c = s_cnum[3];
        const int M = n0c + n1c + n2c + n3c;
        unsigned int e[6]; bool val[6];
#pragma unroll
        for (int s = 0; s < 6; ++s) {
            const int i = lane + 64 * s;
            val[s] = (i < M);
            unsigned int v = 0;
            if (val[s]) {
                int ii = i;
                if (ii < n0c) v = s_cand[0][ii];
                else { ii -= n0c;
                    if (ii < n1c) v = s_cand[1][ii];
                    else { ii -= n1c;
                        if (ii < n2c) v = s_cand[2][ii];
                        else v = s_cand[3][ii - n2c]; } }
            }
            e[s] = v;
        }
        unsigned int T = 0;
#pragma unroll
        for (int b = 15; b >= 0; --b) {
            const unsigned int tc = T | (1u << b);
            int c = 0;
#pragma unroll
            for (int s = 0; s < 6; ++s) c += (int)(val[s] && (e[s] >> 16) >= tc);
#pragma unroll
            for (int off = 1; off < 64; off <<= 1) c += __shfl_xor(c, off);
            if (c >= KSEL) T = tc;
        }
        int cgt = 0;
#pragma unroll
        for (int s = 0; s < 6; ++s) cgt += (int)(val[s] && (e[s] >> 16) > T);
#pragma unroll
        for (int off = 1; off < 64; off <<= 1) cgt += __shfl_xor(cgt, off);
        int tneed = KSEL - cgt;
        if (tneed < 0) tneed = 0;
        if (tneed > 40) tneed = 40;

        // extract tneed lowest-gi ties (key == T) via iterative butterfly-min
        bool taken[6] = {false, false, false, false, false, false};
        for (int k = 0; k < tneed; ++k) {
            int m = 0x7fffffff;
#pragma unroll
            for (int s = 0; s < 6; ++s)
                if (val[s] && !taken[s] && (e[s] >> 16) == T) {
                    const int g = (int)(e[s] & 0xFFFFu);
                    if (g < m) m = g;
                }
#pragma unroll
            for (int off = 1; off < 64; off <<= 1) {
                const int o = __shfl_xor(m, off);
                if (o < m) m = o;
            }
            if (m == 0x7fffffff) { if (lane == 0) s_selgi[k] = -1; continue; }
#pragma unroll
            for (int s = 0; s < 6; ++s)
                if (val[s] && !taken[s] && (e[s] >> 16) == T && (int)(e[s] & 0xFFFFu) == m) {
                    taken[s] = true;          // unique gi -> exactly one lane
                    s_selgi[k] = m;
                }
        }
        if (lane == 0) { s_tau = T; s_nsel = tneed; }
    }
    __syncthreads();                         // barrier 2

    // ---- predicated writeback: fill 0xFBFF, keep selected (patched-finite)
    const unsigned int T = s_tau;
    const int nsel = s_nsel;
    unsigned long long cons = 0ull;
    for (int k = 0; k < nsel; ++k) {
        const int g = s_selgi[k];
        if (g >= 0 && ((g >> 3) & 255) == t) cons |= 1ull << (((g >> 11) << 3) | (g & 7));
    }
    uint4* wp4 = (uint4*)rowp;
#pragma unroll
    for (int j = 0; j < 8; ++j) {
        const unsigned int* w = (const unsigned int*)&d[j];
        uint4 o;
        unsigned int* ow = (unsigned int*)&o;
#pragma unroll
        for (int q = 0; q < 4; ++q) {
            const unsigned int klo = w[q] & 0xFFFFu, khi = w[q] >> 16;
            const int ord = j * 8 + q * 2;
            const bool sl = (klo > T) || ((cons >> ord) & 1ull);
            const bool sh = (khi > T) || ((cons >> (ord + 1)) & 1ull);
            const unsigned int lo = sl ? patch16(inv_key(klo)) : 0xFBFFu;
            const unsigned int hi = sh ? patch16(inv_key(khi)) : 0xFBFFu;
            ow[q] = lo | (hi << 16);
        }
        wp4[j * 256 + t] = o;
    }
}

// ---------------------------------------------------------------- launch
extern "C" void kernel_launch(void* const* d_in, const int* in_sizes, int n_in,
                              void* d_out, int out_size, void* d_ws, size_t ws_size,
                              hipStream_t stream) {
    const unsigned short* x  = (const unsigned short*)d_in[0];   // [4096 x 256] f16
    const unsigned short* xn = (const unsigned short*)d_in[1];   // [16384 x 256] f16
    unsigned short* out = (unsigned short*)d_out;                // [4096 x 16384] f16
    float* ws = (float*)d_ws;

    const bool use_ws = ws_size >= (size_t)(Q + NN) * sizeof(float);
    if (use_ws) {
        norms_kernel<<<Q + NN, 64, 0, stream>>>(x, xn, ws);
        gemm_sim_kernel<true><<<dim3(NN / 128, Q / 128), 256, 0, stream>>>(x, xn, ws, out);
    } else {
        gemm_sim_kernel<false><<<dim3(NN / 128, Q / 128), 256, 0, stream>>>(x, xn, nullptr, out);
    }
    topk_kernel<<<Q, 256, 0, stream>>>(out);
}